// Round 19
// baseline (23.852 us; speedup 1.0000x reference)
//
#include <hip/hip_runtime.h>

static constexpr int C_IN  = 64;
static constexpr int O_OUT = 64;
static constexpr int HH    = 28;
static constexpr int WW    = 28;
static constexpr int CKK   = C_IN * 9;     // 576

#define RDLANE(v, ln) __uint_as_float(__builtin_amdgcn_readlane(__float_as_uint(v), (ln)))

// R19 = R17 verbatim EXCEPT weights come from 5 lane-distributed VGPRs via
// v_readlane (compile-time lanes, full c x k unroll) instead of in-loop
// s_load. Purpose: decisive S1 probe - is the ~5.3us residual stall the
// SMEM weight-fetch latency? Main loop's ONLY memory = 9 vmcnt gathers.
// Products stay pinned: 12 VALU per tap (4 mul[s,v], 4 rndne, 4 add).
__global__ __launch_bounds__(512, 8) void conv2d_quant_kernel(
    const float* __restrict__ x,
    const float* __restrict__ wgt,
    const float* __restrict__ bias,
    float* __restrict__ out)
{
    __shared__ float4 red4[8][64];       // 4 KB: per-wave partial accumulators

    const int tid = threadIdx.x;
    const int b   = blockIdx.z;
    const int y0  = blockIdx.y * 2;
    const int o0  = blockIdx.x * 4;

    const int lane = tid & 63;
    const int wid  = __builtin_amdgcn_readfirstlane(tid >> 6);  // 0..7 = c-slice

    // ---- preload wave's 288 weights (4o x 8c x 9) into 5 VGPRs ----
    // flat f = o_rel*72 + c_rel*9 + k ; reg = f>>6, lane = f&63
    float wv0, wv1, wv2, wv3, wv4;
    {
        const float* wb = wgt + o0 * CKK + wid * 72;
        int f, o;
        f = lane;        o = f / 72; wv0 = wb[o * CKK + (f - o * 72)];
        f = 64 + lane;   o = f / 72; wv1 = wb[o * CKK + (f - o * 72)];
        f = 128 + lane;  o = f / 72; wv2 = wb[o * CKK + (f - o * 72)];
        f = 192 + lane;  o = f / 72; wv3 = wb[o * CKK + (f - o * 72)];
        f = 256 + lane; if (f > 287) f = 287;
                         o = f / 72; wv4 = wb[o * CKK + (f - o * 72)];
    }

    const int l    = (lane < 56) ? lane : 0;   // lanes 56..63 shadow lane 0 (no store)
    const int row  = l / 28;                   // 0..1
    const int px   = l - row * 28;             // 0..27

    // ---- per-lane window offsets (clamped in-bounds) + {0,8} halo masks ----
    int   off[9];
    float m8[9];
    #pragma unroll
    for (int i = 0; i < 3; ++i) {
        const int gy = y0 + row - 1 + i;
        const int cy = gy < 0 ? 0 : (gy > HH - 1 ? HH - 1 : gy);
        #pragma unroll
        for (int j = 0; j < 3; ++j) {
            const int gx = px - 1 + j;
            const int cx = gx < 0 ? 0 : (gx > WW - 1 ? WW - 1 : gx);
            const bool ok = ((unsigned)gy < (unsigned)HH) && ((unsigned)gx < (unsigned)WW);
            off[i * 3 + j] = cy * WW + cx;
            m8[i * 3 + j]  = ok ? 8.0f : 0.0f;   // folds x*8 scale + zero halo
        }
    }

    const float* xp = x + (b * C_IN + wid * 8) * (HH * WW);

    float a0 = 0.0f, a1 = 0.0f, a2 = 0.0f, a3 = 0.0f;

    #pragma unroll
    for (int c = 0; c < 8; ++c) {          // FULL unroll: compile-time readlane lanes
        const float* xc = xp + c * (HH * WW);
        float xm[9];
        #pragma unroll
        for (int k = 0; k < 9; ++k)
            xm[k] = xc[off[k]] * m8[k];    // global gather (vmcnt only) + mask*8

        // per-product clamp omitted: |8*x*w| <= ~10 << 128 (validated absmax=0)
        #pragma unroll
        for (int k = 0; k < 9; ++k) {
            const int base = c * 9 + k;    // compile-time
            const int f0 = base,       f1 = 72 + base;
            const int f2 = 144 + base, f3 = 216 + base;
            const float w0 = (f0 < 64) ? RDLANE(wv0, f0 & 63) : RDLANE(wv1, f0 & 63);
            const float w1 = (f1 < 128) ? RDLANE(wv1, f1 & 63) : RDLANE(wv2, f1 & 63);
            const float w2 = (f2 < 192) ? RDLANE(wv2, f2 & 63) : RDLANE(wv3, f2 & 63);
            const float w3 = (f3 < 256) ? RDLANE(wv3, f3 & 63) : RDLANE(wv4, f3 & 63);

            float t0, t1, t2, t3;
            asm("v_mul_f32 %4, %9, %8\n\t"
                "v_mul_f32 %5, %10, %8\n\t"
                "v_mul_f32 %6, %11, %8\n\t"
                "v_mul_f32 %7, %12, %8\n\t"
                "v_rndne_f32 %4, %4\n\t"
                "v_rndne_f32 %5, %5\n\t"
                "v_rndne_f32 %6, %6\n\t"
                "v_rndne_f32 %7, %7\n\t"
                "v_add_f32 %0, %0, %4\n\t"
                "v_add_f32 %1, %1, %5\n\t"
                "v_add_f32 %2, %2, %6\n\t"
                "v_add_f32 %3, %3, %7"
                : "+v"(a0), "+v"(a1), "+v"(a2), "+v"(a3),
                  "=&v"(t0), "=&v"(t1), "=&v"(t2), "=&v"(t3)
                : "v"(xm[k]),
                  "s"(w0), "s"(w1), "s"(w2), "s"(w3));
        }
    }

    // ---- combine c-slices (integer-valued f32 sums -> exact in any order) ----
    red4[wid][lane] = make_float4(a0, a1, a2, a3);
    __syncthreads();

    if (tid < 56) {
        float4 s = red4[0][tid];
        #pragma unroll
        for (int w = 1; w < 8; ++w) {
            const float4 p = red4[w][tid];
            s.x += p.x; s.y += p.y; s.z += p.z; s.w += p.w;
        }
        const float acc[4] = {s.x, s.y, s.z, s.w};
        const int row2 = tid / 28;
        const int px2  = tid - row2 * 28;
        const int y    = y0 + row2;
        #pragma unroll
        for (int q = 0; q < 4; ++q) {
            const float b8 = bias[o0 + q] * 8.0f;
            float v = fminf(fmaxf(acc[q], -128.0f), 127.0f);
            v = rintf(v + b8);
            v = fminf(fmaxf(v, -128.0f), 127.0f) * 0.125f;
            out[((b * O_OUT + o0 + q) * HH + y) * WW + px2] = v;
        }
    }
}

extern "C" void kernel_launch(void* const* d_in, const int* in_sizes, int n_in,
                              void* d_out, int out_size, void* d_ws, size_t ws_size,
                              hipStream_t stream)
{
    const float* x    = (const float*)d_in[0];
    const float* wgt  = (const float*)d_in[1];
    const float* bias = (const float*)d_in[2];
    float* out        = (float*)d_out;

    dim3 grid(16, 14, 4);   // o-quads x row-pairs x batch = 896 blocks, 8 waves each
    conv2d_quant_kernel<<<grid, dim3(512), 0, stream>>>(x, wgt, bias, out);
}

// Round 20
// 15.956 us; speedup vs baseline: 1.4949x; 1.4949x over previous
//
#include <hip/hip_runtime.h>

static constexpr int C_IN  = 64;
static constexpr int O_OUT = 64;
static constexpr int HH    = 28;
static constexpr int WW    = 28;

// R20 = R17 byte-identical EXCEPT full c-unroll (was unroll 2).
// Purpose: widen the compiler's load-hoisting window from 18 to 72 gathers
// so vmcnt/lgkm waits amortize across the whole 8-iteration body.
// Products stay pinned: per tap k exactly 12 VALU (4x v_mul[s,v],
// 4x v_rndne, 4x v_add); weights via wave-uniform s_load ("s" operands).
__global__ __launch_bounds__(512, 8) void conv2d_quant_kernel(
    const float* __restrict__ x,
    const float* __restrict__ wgt,
    const float* __restrict__ bias,
    float* __restrict__ out)
{
    __shared__ float4 red4[8][64];       // 4 KB: per-wave partial accumulators

    const int tid = threadIdx.x;
    const int b   = blockIdx.z;
    const int y0  = blockIdx.y * 2;
    const int o0  = blockIdx.x * 4;

    const int lane = tid & 63;
    const int wid  = __builtin_amdgcn_readfirstlane(tid >> 6);  // 0..7 = c-slice
    const int l    = (lane < 56) ? lane : 0;   // lanes 56..63 shadow lane 0 (no store)
    const int row  = l / 28;                   // 0..1
    const int px   = l - row * 28;             // 0..27

    // ---- per-lane window offsets (clamped in-bounds) + {0,8} halo masks ----
    int   off[9];
    float m8[9];
    #pragma unroll
    for (int i = 0; i < 3; ++i) {
        const int gy = y0 + row - 1 + i;
        const int cy = gy < 0 ? 0 : (gy > HH - 1 ? HH - 1 : gy);
        #pragma unroll
        for (int j = 0; j < 3; ++j) {
            const int gx = px - 1 + j;
            const int cx = gx < 0 ? 0 : (gx > WW - 1 ? WW - 1 : gx);
            const bool ok = ((unsigned)gy < (unsigned)HH) && ((unsigned)gx < (unsigned)WW);
            off[i * 3 + j] = cy * WW + cx;
            m8[i * 3 + j]  = ok ? 8.0f : 0.0f;   // folds x*8 scale + zero halo
        }
    }

    const float* xp  = x + (b * C_IN + wid * 8) * (HH * WW);
    const float* wp0 = wgt + (o0 + 0) * (C_IN * 9) + wid * 8 * 9;
    const float* wp1 = wgt + (o0 + 1) * (C_IN * 9) + wid * 8 * 9;
    const float* wp2 = wgt + (o0 + 2) * (C_IN * 9) + wid * 8 * 9;
    const float* wp3 = wgt + (o0 + 3) * (C_IN * 9) + wid * 8 * 9;

    float a0 = 0.0f, a1 = 0.0f, a2 = 0.0f, a3 = 0.0f;

    #pragma unroll
    for (int c = 0; c < 8; ++c) {
        const float* xc = xp + c * (HH * WW);
        float xm[9];
        #pragma unroll
        for (int k = 0; k < 9; ++k)
            xm[k] = xc[off[k]] * m8[k];        // global gather (L1/L2-hot) + mask*8

        const float* wr0 = wp0 + c * 9;        // wave-uniform -> s_load -> "s" operand
        const float* wr1 = wp1 + c * 9;
        const float* wr2 = wp2 + c * 9;
        const float* wr3 = wp3 + c * 9;

        // per-product clamp omitted: |8*x*w| <= ~10 << 128 (validated absmax=0)
        #pragma unroll
        for (int k = 0; k < 9; ++k) {
            float t0, t1, t2, t3;
            asm("v_mul_f32 %4, %9, %8\n\t"
                "v_mul_f32 %5, %10, %8\n\t"
                "v_mul_f32 %6, %11, %8\n\t"
                "v_mul_f32 %7, %12, %8\n\t"
                "v_rndne_f32 %4, %4\n\t"
                "v_rndne_f32 %5, %5\n\t"
                "v_rndne_f32 %6, %6\n\t"
                "v_rndne_f32 %7, %7\n\t"
                "v_add_f32 %0, %0, %4\n\t"
                "v_add_f32 %1, %1, %5\n\t"
                "v_add_f32 %2, %2, %6\n\t"
                "v_add_f32 %3, %3, %7"
                : "+v"(a0), "+v"(a1), "+v"(a2), "+v"(a3),
                  "=&v"(t0), "=&v"(t1), "=&v"(t2), "=&v"(t3)
                : "v"(xm[k]),
                  "s"(wr0[k]), "s"(wr1[k]), "s"(wr2[k]), "s"(wr3[k]));
        }
    }

    // ---- combine c-slices (integer-valued f32 sums -> exact in any order) ----
    red4[wid][lane] = make_float4(a0, a1, a2, a3);
    __syncthreads();

    if (tid < 56) {
        float4 s = red4[0][tid];
        #pragma unroll
        for (int w = 1; w < 8; ++w) {
            const float4 p = red4[w][tid];
            s.x += p.x; s.y += p.y; s.z += p.z; s.w += p.w;
        }
        const float acc[4] = {s.x, s.y, s.z, s.w};
        const int row2 = tid / 28;
        const int px2  = tid - row2 * 28;
        const int y    = y0 + row2;
        #pragma unroll
        for (int q = 0; q < 4; ++q) {
            const float b8 = bias[o0 + q] * 8.0f;
            float v = fminf(fmaxf(acc[q], -128.0f), 127.0f);
            v = rintf(v + b8);
            v = fminf(fmaxf(v, -128.0f), 127.0f) * 0.125f;
            out[((b * O_OUT + o0 + q) * HH + y) * WW + px2] = v;
        }
    }
}

extern "C" void kernel_launch(void* const* d_in, const int* in_sizes, int n_in,
                              void* d_out, int out_size, void* d_ws, size_t ws_size,
                              hipStream_t stream)
{
    const float* x    = (const float*)d_in[0];
    const float* wgt  = (const float*)d_in[1];
    const float* bias = (const float*)d_in[2];
    float* out        = (float*)d_out;

    dim3 grid(16, 14, 4);   // o-quads x row-pairs x batch = 896 blocks, 8 waves each
    conv2d_quant_kernel<<<grid, dim3(512), 0, stream>>>(x, wgt, bias, out);
}